// Round 5
// baseline (8586.435 us; speedup 1.0000x reference)
//
#include <hip/hip_runtime.h>

#define D_ 512
#define FF_ 1024
#define L_ 4
#define A_ 32
#define B_ 1024
#define STEPS_ 64
#define RB_ 0.0625f   // rescue band; main-dot err sigma ~1.8e-3 => 34 sigma

typedef __attribute__((ext_vector_type(8))) short bf16x8;
typedef __attribute__((ext_vector_type(4))) float f32x4;
#define MFMA16(a,b,c) __builtin_amdgcn_mfma_f32_16x16x32_bf16(a,b,c,0,0,0)

__device__ __forceinline__ unsigned rne16(float f) {
    unsigned u = __float_as_uint(f);
    return (u + 0x7fffu + ((u >> 16) & 1u)) >> 16;
}
__device__ __forceinline__ float fb(unsigned hu) { return __uint_as_float(hu << 16); }

// ---------------- Wvo[l] = Wv[l] @ Wo[l], emitted as split-bf16 MFMA fragments --
// Fragment layout (16x16x32 bf16 B-operand), R3-verified: frag(l,nt,kk): lane
// holds B[k = kk*32 + (lane>>4)*8 + j][n = nt*16 + (lane&15)], j=0..7 (16B/lane).
__global__ __launch_bounds__(256) void wvo_kernel(
    const float* __restrict__ Wv, const float* __restrict__ Wo,
    unsigned* __restrict__ Whi, unsigned* __restrict__ Wlo)
{
    __shared__ float wvt[16][D_];
    int bx  = blockIdx.x;
    int l   = bx >> 6;
    int rem = bx & 63;
    int k0  = (rem >> 1) * 16;
    int n   = (rem & 1) * 256 + threadIdx.x;

    const float* wvbase = Wv + (size_t)l * D_ * D_ + (size_t)k0 * D_;
    for (int idx = threadIdx.x; idx < 16 * D_; idx += 256)
        wvt[idx >> 9][idx & (D_ - 1)] = wvbase[idx];
    __syncthreads();

    float acc[16];
#pragma unroll
    for (int kk = 0; kk < 16; ++kk) acc[kk] = 0.f;

    const float* wop = Wo + (size_t)l * D_ * D_ + n;
    for (int m = 0; m < D_; m += 4) {
        float w0 = wop[(m + 0) * D_];
        float w1 = wop[(m + 1) * D_];
        float w2 = wop[(m + 2) * D_];
        float w3 = wop[(m + 3) * D_];
#pragma unroll
        for (int kk = 0; kk < 16; ++kk) {
            float4 wv4 = *(const float4*)&wvt[kk][m];
            acc[kk] += wv4.x * w0 + wv4.y * w1 + wv4.z * w2 + wv4.w * w3;
        }
    }
    int nt = n >> 4, ln15 = n & 15;
    int kkblk = k0 >> 5;
    int gbase = (k0 & 31) >> 3;
#pragma unroll
    for (int gi = 0; gi < 2; ++gi) {
        int lane_s = ((gbase + gi) << 4) | ln15;
        size_t fbase = ((((size_t)l * 32 + nt) * 16 + kkblk) * 64 + lane_s) * 4;
#pragma unroll
        for (int jp = 0; jp < 4; ++jp) {
            float v0 = acc[gi * 8 + jp * 2], v1 = acc[gi * 8 + jp * 2 + 1];
            unsigned h0 = rne16(v0), h1 = rne16(v1);
            Whi[fbase + jp] = h0 | (h1 << 16);
            float r0 = v0 - fb(h0), r1 = v1 - fb(h1);
            Wlo[fbase + jp] = rne16(r0) | (rne16(r1) << 16);
        }
    }
}

// ---------------- bvo[l] = bv[l] @ Wo[l] + bo[l] -------------------------------
__global__ __launch_bounds__(256) void bvo_kernel(
    const float* __restrict__ bv, const float* __restrict__ bo,
    const float* __restrict__ Wo, float* __restrict__ bvo)
{
    int l = blockIdx.x >> 1;
    int n = (blockIdx.x & 1) * 256 + threadIdx.x;
    float acc = bo[l * D_ + n];
    const float* wop = Wo + (size_t)l * D_ * D_ + n;
    const float* bvp = bv + l * D_;
    for (int m = 0; m < D_; ++m) acc += bvp[m] * wop[m * D_];
    bvo[l * D_ + n] = acc;
}

// ---------------- Wf1 -> bf16 MFMA fragments (hi only) -------------------------
__global__ __launch_bounds__(64) void packwf1_kernel(
    const float* __restrict__ Wf1, unsigned* __restrict__ Pf)
{
    int bid = blockIdx.x;              // 4*64*16 = 4096
    int lane = threadIdx.x;
    int l  = bid >> 10;
    int nt = (bid >> 4) & 63;
    int kk = bid & 15;
    int krow = kk * 32 + (lane >> 4) * 8;
    int n    = nt * 16 + (lane & 15);
    const float* src = Wf1 + ((size_t)l * D_ + krow) * FF_ + n;
    unsigned o[4];
#pragma unroll
    for (int jp = 0; jp < 4; ++jp) {
        unsigned a = rne16(src[(2 * jp) * FF_]);
        unsigned b = rne16(src[(2 * jp + 1) * FF_]);
        o[jp] = a | (b << 16);
    }
    size_t fbase = (((size_t)(l * 64 + nt) * 16 + kk) * 64 + lane) * 4;
    Pf[fbase + 0] = o[0]; Pf[fbase + 1] = o[1];
    Pf[fbase + 2] = o[2]; Pf[fbase + 3] = o[3];
}

// ---------------- LN + A-frag pack (R3-verified body; 4 samples per call) ------
// Thread (sg = tid>>8, r = tid&255) handles elements c=2r, 2r+1 of sample sg.
// Writes hi to A-row sg, lo to A-row sg+4; rows 8..15 stay zero (zeroed once).
__device__ __forceinline__ void layer_norm_frag8(
    const float* __restrict__ xbase,       // xb + gsel*4*D_
    unsigned* __restrict__ afrag,          // afrag2[gsel]
    const float* __restrict__ g, const float* __restrict__ bt,
    float (*red)[4][2], int sg, int r)
{
    int c = 2 * r;
    float v0 = xbase[sg * D_ + c], v1 = xbase[sg * D_ + c + 1];
    float s  = v0 + v1;
    float ss = v0 * v0 + v1 * v1;
#pragma unroll
    for (int m = 1; m < 64; m <<= 1) {
        s  += __shfl_xor(s, m);
        ss += __shfl_xor(ss, m);
    }
    if ((r & 63) == 0) { red[sg][r >> 6][0] = s; red[sg][r >> 6][1] = ss; }
    __syncthreads();
    float S  = red[sg][0][0] + red[sg][1][0] + red[sg][2][0] + red[sg][3][0];
    float SS = red[sg][0][1] + red[sg][1][1] + red[sg][2][1] + red[sg][3][1];
    float mean = S * (1.f / 512.f);
    float var  = SS * (1.f / 512.f) - mean * mean;
    float rstd = 1.0f / sqrtf(var + 1e-5f);
    float h0 = (v0 - mean) * rstd * g[c]     + bt[c];
    float h1 = (v1 - mean) * rstd * g[c + 1] + bt[c + 1];
    unsigned u0 = rne16(h0), u1 = rne16(h1);
    float l0 = h0 - fb(u0), l1 = h1 - fb(u1);
    int kk = c >> 5, gg = (c & 31) >> 3, jp = (c & 7) >> 1;
    afrag[(kk * 64 + ((gg << 4) | sg))       * 4 + jp] = u0 | (u1 << 16);
    afrag[(kk * 64 + ((gg << 4) | (sg + 4))) * 4 + jp] = rne16(l0) | (rne16(l1) << 16);
    __syncthreads();
}

// ---------------- persistent recurrence kernel: 8 samples via TWO R3 tiles -----
__global__ __launch_bounds__(1024, 4) void smain(
    const float* __restrict__ init_state,
    const float* __restrict__ acts,
    const float* __restrict__ Wa,  const float* __restrict__ ba,
    const float* __restrict__ ln1g, const float* __restrict__ ln1b,
    const float* __restrict__ ln2g, const float* __restrict__ ln2b,
    const float* __restrict__ Wf1, const float* __restrict__ bf1,
    const float* __restrict__ Wf2, const float* __restrict__ bf2,
    const float* __restrict__ lifth,
    const float* __restrict__ Wr,  const float* __restrict__ br,
    const unsigned* __restrict__ Whi, const unsigned* __restrict__ Wlo,
    const unsigned* __restrict__ Pf, const float* __restrict__ bvo,
    float* __restrict__ out_states, float* __restrict__ out_rewards,
    float* __restrict__ out_final)
{
    __shared__ __align__(16) unsigned afrag2[2][16 * 64 * 4];  // 2 x 16KB A-tiles
    __shared__ __align__(16) float xb[8 * D_];                 // residual rows
    __shared__ unsigned char sb8[8][D_];                       // carried spikes
    __shared__ float areg[8][A_];
    __shared__ float red[4][4][2];
    __shared__ float rr[16];
    __shared__ int   fire_cnt, resc_cnt;
    __shared__ int   fire_list[256];
    __shared__ int   rescue_list[64];

    const int tid  = threadIdx.x;
    const int sg   = tid >> 8;      // 0..3 within a 4-sample group
    const int r    = tid & 255;
    const int wv   = tid >> 6;      // wave 0..15
    const int lane = tid & 63;
    const int b0   = blockIdx.x * 8;

    {   // zero both A-frag tiles once: rows 8..15 stay zero forever (R3 invariant)
        unsigned* az = (unsigned*)afrag2;
#pragma unroll
        for (int z = 0; z < 8; ++z) az[tid + z * 1024] = 0;
    }
    __syncthreads();

    for (int t = 0; t < STEPS_; ++t) {
        if (tid < 256) {
            int s2 = tid >> 5, j = tid & 31;
            areg[s2][j] = acts[(size_t)(b0 + s2) * (STEPS_ * A_) + t * A_ + j];
        }
        __syncthreads();

        // ---- x = state + a @ Wa + ba  (two 4-sample groups, R3 body) ----
#pragma unroll
        for (int gsel = 0; gsel < 2; ++gsel) {
            int s = gsel * 4 + sg;
            float2 st;
            if (t == 0) st = *(const float2*)&init_state[(size_t)(b0 + s) * D_ + 2 * r];
            else        st = make_float2((float)sb8[s][2 * r], (float)sb8[s][2 * r + 1]);
            float2 xv;
            xv.x = st.x + ba[2 * r];
            xv.y = st.y + ba[2 * r + 1];
#pragma unroll
            for (int j = 0; j < A_; ++j) {
                float av = areg[s][j];
                float2 w2 = *(const float2*)(Wa + j * D_ + 2 * r);
                xv.x += av * w2.x; xv.y += av * w2.y;
            }
            xb[s * D_ + 2 * r] = xv.x; xb[s * D_ + 2 * r + 1] = xv.y;
        }
        __syncthreads();

        for (int l = 0; l < L_; ++l) {
            // ---- LN1: both groups -> afrag tiles ----
            layer_norm_frag8(xb,           afrag2[0], ln1g + l * D_, ln1b + l * D_, red, sg, r);
            layer_norm_frag8(xb + 4 * D_,  afrag2[1], ln1g + l * D_, ln1b + l * D_, red, sg, r);

            // ---- GEMM1 (dual-tile MFMA): xb += (hhi+hlo) @ (Whi+Wlo) + bvo ----
            {
                const bf16x8* A0 = (const bf16x8*)(afrag2[0]);
                const bf16x8* A1 = (const bf16x8*)(afrag2[1]);
                const size_t lb = (size_t)l * (32 * 16 * 64);
                const bf16x8* BH = (const bf16x8*)Whi + lb;
                const bf16x8* BL = (const bf16x8*)Wlo + lb;
                const int nt0 = 2 * wv, nt1 = nt0 + 1;
                f32x4 z = {0.f, 0.f, 0.f, 0.f};
                f32x4 cA1a = z, cA2a = z, cA1b = z, cA2b = z;
                f32x4 cB1a = z, cB2a = z, cB1b = z, cB2b = z;
#pragma unroll 2
                for (int kk = 0; kk < 16; ++kk) {
                    bf16x8 aA = A0[kk * 64 + lane];
                    bf16x8 aB = A1[kk * 64 + lane];
                    bf16x8 h0 = BH[(nt0 * 16 + kk) * 64 + lane];
                    bf16x8 g0 = BL[(nt0 * 16 + kk) * 64 + lane];
                    bf16x8 h1 = BH[(nt1 * 16 + kk) * 64 + lane];
                    bf16x8 g1 = BL[(nt1 * 16 + kk) * 64 + lane];
                    cA1a = MFMA16(aA, h0, cA1a); cA2a = MFMA16(aA, g0, cA2a);
                    cA1b = MFMA16(aA, h1, cA1b); cA2b = MFMA16(aA, g1, cA2b);
                    cB1a = MFMA16(aB, h0, cB1a); cB2a = MFMA16(aB, g0, cB2a);
                    cB1b = MFMA16(aB, h1, cB1b); cB2b = MFMA16(aB, g1, cB2b);
                }
                // R3-verified combine: C row s (hi) + row s+4 (lo) via shfl +16
                const float* bvog = bvo + l * D_;
#pragma unroll
                for (int s = 0; s < 4; ++s) {
                    float pa = cA1a[s] + cA2a[s]; float qa = __shfl(pa, (lane & 15) + 16);
                    float pb = cA1b[s] + cA2b[s]; float qb = __shfl(pb, (lane & 15) + 16);
                    float pc = cB1a[s] + cB2a[s]; float qc = __shfl(pc, (lane & 15) + 16);
                    float pd = cB1b[s] + cB2b[s]; float qd = __shfl(pd, (lane & 15) + 16);
                    if (lane < 16) {
                        int ca = nt0 * 16 + lane, cb = nt1 * 16 + lane;
                        xb[s * D_ + ca]       += pa + qa + bvog[ca];
                        xb[s * D_ + cb]       += pb + qb + bvog[cb];
                        xb[(s + 4) * D_ + ca] += pc + qc + bvog[ca];
                        xb[(s + 4) * D_ + cb] += pd + qd + bvog[cb];
                    }
                }
            }
            __syncthreads();

            if (tid == 0) { fire_cnt = 0; resc_cnt = 0; }

            // ---- LN2: both groups -> afrag tiles ----
            layer_norm_frag8(xb,          afrag2[0], ln2g + l * D_, ln2b + l * D_, red, sg, r);
            layer_norm_frag8(xb + 4 * D_, afrag2[1], ln2g + l * D_, ln2b + l * D_, red, sg, r);

            // ---- GEMM2 (dual-tile): pre = h2 @ Wf1bf + bf1 - 2 ; detect -------
            {
                const bf16x8* A0 = (const bf16x8*)(afrag2[0]);
                const bf16x8* A1 = (const bf16x8*)(afrag2[1]);
                const bf16x8* PB = (const bf16x8*)Pf + (size_t)l * (64 * 16 * 64);
                const int m0 = 4 * wv;
                f32x4 z = {0.f, 0.f, 0.f, 0.f};
                f32x4 pA0 = z, pA1 = z, pA2 = z, pA3 = z;
                f32x4 pB0 = z, pB1 = z, pB2 = z, pB3 = z;
#pragma unroll 2
                for (int kk = 0; kk < 16; ++kk) {
                    bf16x8 aA = A0[kk * 64 + lane];
                    bf16x8 aB = A1[kk * 64 + lane];
                    bf16x8 b0 = PB[((m0 + 0) * 16 + kk) * 64 + lane];
                    bf16x8 b1 = PB[((m0 + 1) * 16 + kk) * 64 + lane];
                    bf16x8 b2 = PB[((m0 + 2) * 16 + kk) * 64 + lane];
                    bf16x8 b3 = PB[((m0 + 3) * 16 + kk) * 64 + lane];
                    pA0 = MFMA16(aA, b0, pA0); pA1 = MFMA16(aA, b1, pA1);
                    pA2 = MFMA16(aA, b2, pA2); pA3 = MFMA16(aA, b3, pA3);
                    pB0 = MFMA16(aB, b0, pB0); pB1 = MFMA16(aB, b1, pB1);
                    pB2 = MFMA16(aB, b2, pB2); pB3 = MFMA16(aB, b3, pB3);
                }
                const float* bf1g = bf1 + l * FF_;
#pragma unroll
                for (int s = 0; s < 4; ++s) {
                    float vA0 = pA0[s]; float wA0 = __shfl(vA0, (lane & 15) + 16);
                    float vA1 = pA1[s]; float wA1 = __shfl(vA1, (lane & 15) + 16);
                    float vA2 = pA2[s]; float wA2 = __shfl(vA2, (lane & 15) + 16);
                    float vA3 = pA3[s]; float wA3 = __shfl(vA3, (lane & 15) + 16);
                    float vB0 = pB0[s]; float wB0 = __shfl(vB0, (lane & 15) + 16);
                    float vB1 = pB1[s]; float wB1 = __shfl(vB1, (lane & 15) + 16);
                    float vB2 = pB2[s]; float wB2 = __shfl(vB2, (lane & 15) + 16);
                    float vB3 = pB3[s]; float wB3 = __shfl(vB3, (lane & 15) + 16);
                    if (lane < 16) {
                        float sumA[4] = {vA0 + wA0, vA1 + wA1, vA2 + wA2, vA3 + wA3};
                        float sumB[4] = {vB0 + wB0, vB1 + wB1, vB2 + wB2, vB3 + wB3};
#pragma unroll
                        for (int q = 0; q < 4; ++q) {
                            int n = (m0 + q) * 16 + lane;
                            float bb = bf1g[n] - 2.0f;
                            float prA = sumA[q] + bb;
                            if (prA > RB_) {
                                int idx = atomicAdd(&fire_cnt, 1);
                                if (idx < 256) fire_list[idx] = (s << 12) | n;
                            } else if (prA > -RB_) {
                                int idx = atomicAdd(&resc_cnt, 1);
                                if (idx < 64) rescue_list[idx] = (s << 12) | n;
                            }
                            float prB = sumB[q] + bb;
                            if (prB > RB_) {
                                int idx = atomicAdd(&fire_cnt, 1);
                                if (idx < 256) fire_list[idx] = ((s + 4) << 12) | n;
                            } else if (prB > -RB_) {
                                int idx = atomicAdd(&resc_cnt, 1);
                                if (idx < 64) rescue_list[idx] = ((s + 4) << 12) | n;
                            }
                        }
                    }
                }
            }
            __syncthreads();

            // ---- rescue: near-fp32 recompute (h2 = hi+lo) of near-threshold ----
            {
                int rc = resc_cnt; if (rc > 64) rc = 64;
                for (int e = 0; e < rc; ++e) {
                    int ent = rescue_list[e];
                    int i = ent >> 12, n = ent & 4095;
                    int tile = i >> 2, ri = i & 3;
                    float p = 0.f;
                    if (tid < D_) {
                        int k = tid;
                        int kk = k >> 5, gg = (k & 31) >> 3, jp = (k & 7) >> 1;
                        unsigned sh = (k & 1) ? 16u : 0u;
                        const unsigned* af = afrag2[tile];
                        unsigned whi = af[(kk * 64 + ((gg << 4) | ri))       * 4 + jp];
                        unsigned wlo = af[(kk * 64 + ((gg << 4) | (ri + 4))) * 4 + jp];
                        float h = fb((whi >> sh) & 0xffffu) + fb((wlo >> sh) & 0xffffu);
                        p = h * Wf1[((size_t)l * D_ + k) * FF_ + n];
                    }
#pragma unroll
                    for (int m = 1; m < 64; m <<= 1) p += __shfl_xor(p, m);
                    if ((tid & 63) == 0) rr[tid >> 6] = p;
                    __syncthreads();
                    if (tid == 0) {
                        float dot = 0.f;
#pragma unroll
                        for (int w2 = 0; w2 < 16; ++w2) dot += rr[w2];
                        float pre = dot + bf1[l * FF_ + n] - 2.0f;
                        if (pre > 0.f) {
                            int idx = atomicAdd(&fire_cnt, 1);
                            if (idx < 256) fire_list[idx] = ent;
                        }
                    }
                    __syncthreads();
                }
            }

            // ---- sparse s @ Wf2 (rare) then + bf2 ----
            {
                int cnt = fire_cnt; if (cnt > 256) cnt = 256;
                for (int e = 0; e < cnt; ++e) {
                    int ent = fire_list[e];
                    int i = ent >> 12, n = ent & 4095;
                    if (tid < D_) xb[i * D_ + tid] += Wf2[(size_t)l * (FF_ * D_) + (size_t)n * D_ + tid];
                }
                if (cnt > 0) __syncthreads();
#pragma unroll
                for (int gsel = 0; gsel < 2; ++gsel) {
                    int s = gsel * 4 + sg;
                    xb[s * D_ + r]       += bf2[l * D_ + r];
                    xb[s * D_ + r + 256] += bf2[l * D_ + r + 256];
                }
            }
            __syncthreads();
        } // layers

        // ---- LIF spike, outputs (nontemporal), reward ----
        for (int gsel = 0; gsel < 2; ++gsel) {
            int s = gsel * 4 + sg;
            float x0 = xb[s * D_ + r], x1 = xb[s * D_ + r + 256];
            float s0 = (x0 > lifth[r])       ? 1.0f : 0.0f;
            float s1 = (x1 > lifth[r + 256]) ? 1.0f : 0.0f;
            sb8[s][r]       = (unsigned char)s0;
            sb8[s][r + 256] = (unsigned char)s1;
            size_t so = ((size_t)(b0 + s) * STEPS_ + t) * D_;
            __builtin_nontemporal_store(s0, &out_states[so + r]);
            __builtin_nontemporal_store(s1, &out_states[so + r + 256]);

            float rs = s0 * Wr[r] + s1 * Wr[r + 256];
#pragma unroll
            for (int m = 1; m < 64; m <<= 1) rs += __shfl_xor(rs, m);
            if ((r & 63) == 0) red[sg][r >> 6][0] = rs;
            __syncthreads();
            if (r == 0)
                __builtin_nontemporal_store(
                    red[sg][0][0] + red[sg][1][0] + red[sg][2][0] + red[sg][3][0] + br[0],
                    &out_rewards[(size_t)(b0 + s) * STEPS_ + t]);
            __syncthreads();
        }
    } // steps

#pragma unroll
    for (int gsel = 0; gsel < 2; ++gsel) {
        int s = gsel * 4 + sg;
        __builtin_nontemporal_store((float)sb8[s][r],       &out_final[(size_t)(b0 + s) * D_ + r]);
        __builtin_nontemporal_store((float)sb8[s][r + 256], &out_final[(size_t)(b0 + s) * D_ + r + 256]);
    }
}

extern "C" void kernel_launch(void* const* d_in, const int* in_sizes, int n_in,
                              void* d_out, int out_size, void* d_ws, size_t ws_size,
                              hipStream_t stream) {
    (void)in_sizes; (void)n_in; (void)out_size; (void)ws_size;
    const float* init_state = (const float*)d_in[0];
    const float* acts  = (const float*)d_in[1];
    const float* Wa    = (const float*)d_in[2];
    const float* ba    = (const float*)d_in[3];
    const float* ln1g  = (const float*)d_in[4];
    const float* ln1b  = (const float*)d_in[5];
    // d_in[6..9] = Wq, bq, Wk, bk: dead (softmax over length-1 axis == 1)
    const float* Wv    = (const float*)d_in[10];
    const float* bv    = (const float*)d_in[11];
    const float* Wo    = (const float*)d_in[12];
    const float* bo    = (const float*)d_in[13];
    const float* ln2g  = (const float*)d_in[14];
    const float* ln2b  = (const float*)d_in[15];
    const float* Wf1   = (const float*)d_in[16];
    const float* bf1   = (const float*)d_in[17];
    const float* Wf2   = (const float*)d_in[18];
    const float* bf2   = (const float*)d_in[19];
    const float* lifth = (const float*)d_in[20];
    const float* Wr    = (const float*)d_in[21];
    const float* br    = (const float*)d_in[22];

    // ws: Whi(2MB) | Wlo(2MB) | Pf(4MB) | bvo(8KB)
    unsigned* Whi = (unsigned*)d_ws;
    unsigned* Wlo = Whi + 524288;
    unsigned* Pf  = Wlo + 524288;
    float*    bvo = (float*)(Pf + 1048576);

    float* out         = (float*)d_out;
    float* out_states  = out;
    float* out_rewards = out + (size_t)B_ * STEPS_ * D_;
    float* out_final   = out_rewards + (size_t)B_ * STEPS_;

    wvo_kernel<<<dim3(256), dim3(256), 0, stream>>>(Wv, Wo, Whi, Wlo);
    bvo_kernel<<<dim3(8),   dim3(256), 0, stream>>>(bv, bo, Wo, bvo);
    packwf1_kernel<<<dim3(4096), dim3(64), 0, stream>>>(Wf1, Pf);
    smain<<<dim3(128), dim3(1024), 0, stream>>>(
        init_state, acts, Wa, ba, ln1g, ln1b, ln2g, ln2b,
        Wf1, bf1, Wf2, bf2, lifth, Wr, br, Whi, Wlo, Pf, bvo,
        out_states, out_rewards, out_final);
}